// Round 1
// baseline (247.725 us; speedup 1.0000x reference)
//
#include <hip/hip_runtime.h>
#include <stdint.h>

// ---------------------------------------------------------------------------
// EfficientSelfAttention: B=8, H=2, N=2048, D=256 (per-head dim = 256)
// out = softmax(QK^T/sqrt(128) masked) V  -> @Wm + bm ; plus mask broadcast.
// Pipeline: k0 (weight prep) -> k1_qk (Q,K) -> k1_v (V^T) -> k2_attn (flash)
//           -> k3_out (out-proj + mask output)
// ---------------------------------------------------------------------------

typedef short bf16x8 __attribute__((ext_vector_type(8)));   // 8 bf16 (4 VGPR)
typedef float f32x16 __attribute__((ext_vector_type(16)));
typedef uint32_t u32x4 __attribute__((ext_vector_type(4)));

#define MFMA(a, b, c) __builtin_amdgcn_mfma_f32_32x32x16_bf16(a, b, c, 0, 0, 0)

__device__ __forceinline__ f32x16 zero16() {
    f32x16 z;
#pragma unroll
    for (int i = 0; i < 16; ++i) z[i] = 0.0f;
    return z;
}

__device__ __forceinline__ unsigned short bf16_rne(float f) {
    uint32_t u = __builtin_bit_cast(uint32_t, f);
    return (unsigned short)((u + 0x7fffu + ((u >> 16) & 1u)) >> 16);
}

__device__ __forceinline__ uint32_t cvt_pk_bf16(float a, float b) {
    uint32_t d;
    asm("v_cvt_pk_bf16_f32 %0, %1, %2" : "=v"(d) : "v"(a), "v"(b));
    return d;
}

__device__ __forceinline__ bf16x8 mk8(uint32_t w0, uint32_t w1, uint32_t w2, uint32_t w3) {
    u32x4 t;
    t[0] = w0; t[1] = w1; t[2] = w2; t[3] = w3;
    return __builtin_bit_cast(bf16x8, t);
}

// load 8 consecutive f32 and pack to bf16x8 (RNE)
__device__ __forceinline__ bf16x8 ldx8(const float* p) {
    float4 xa = *(const float4*)p;
    float4 xb = *(const float4*)(p + 4);
    return mk8(cvt_pk_bf16(xa.x, xa.y), cvt_pk_bf16(xa.z, xa.w),
               cvt_pk_bf16(xb.x, xb.y), cvt_pk_bf16(xb.z, xb.w));
}

// ---------------------------------------------------------------------------
// k0: WqT/WkT/WvT[c][k] = W[k][c] (512x256 bf16), WmT[c][k] = Wm[k][c]
// (256x512 bf16), bias2[b*2048+n] = mask ? -32768*log2e : 0
// ---------------------------------------------------------------------------
__global__ void k0_prep(const float* __restrict__ Wq, const float* __restrict__ Wk,
                        const float* __restrict__ Wv, const float* __restrict__ Wm,
                        const int* __restrict__ mask, unsigned short* __restrict__ WqT,
                        unsigned short* __restrict__ WkT, unsigned short* __restrict__ WvT,
                        unsigned short* __restrict__ WmT, float* __restrict__ bias2) {
    int id = blockIdx.x * 256 + threadIdx.x;
    if (id < 3 * 131072) {
        int seg = id >> 17;
        int j = id & 131071;           // c*256 + k, c in [0,512)
        int c = j >> 8, k = j & 255;
        const float* W = (seg == 0) ? Wq : (seg == 1) ? Wk : Wv;
        unsigned short* WT = (seg == 0) ? WqT : (seg == 1) ? WkT : WvT;
        WT[j] = bf16_rne(W[k * 512 + c]);
    } else if (id < 4 * 131072) {
        int j = id - 3 * 131072;       // c*512 + k, c in [0,256)
        int c = j >> 9, k = j & 511;
        WmT[j] = bf16_rne(Wm[k * 256 + c]);
    } else {
        int j = id - 4 * 131072;
        if (j < 16384)
            bias2[j] = mask[j] ? (-32768.0f * 1.4426950408889634f) : 0.0f;
    }
}

// ---------------------------------------------------------------------------
// k1_qk: Q/K = x @ W + b, output [bh][n][256] bf16.
// grid (128 m-tiles, 8): y>>2 = proj (0=Q,1=K), y&3 = 128-col block.
// ---------------------------------------------------------------------------
__global__ __launch_bounds__(256) void k1_qk(const float* __restrict__ x,
        const unsigned short* __restrict__ WqT, const unsigned short* __restrict__ WkT,
        const float* __restrict__ bq, const float* __restrict__ bk,
        unsigned short* __restrict__ Qb, unsigned short* __restrict__ Kb) {
    const int w = threadIdx.x >> 6, l = threadIdx.x & 63;
    const int l31 = l & 31, hf = l >> 5;
    const int proj = blockIdx.y >> 2, cblk = blockIdx.y & 3;
    const unsigned short* WT = proj ? WkT : WqT;
    const float* bias = proj ? bk : bq;
    unsigned short* Ob = proj ? Kb : Qb;
    const int m0 = blockIdx.x * 128 + w * 32;
    f32x16 acc[4];
#pragma unroll
    for (int i = 0; i < 4; ++i) acc[i] = zero16();
#pragma unroll
    for (int kc = 0; kc < 16; ++kc) {
        bf16x8 a = ldx8(x + (size_t)(m0 + l31) * 256 + kc * 16 + hf * 8);
#pragma unroll
        for (int ct = 0; ct < 4; ++ct) {
            int c = cblk * 128 + ct * 32 + l31;
            bf16x8 bw = *(const bf16x8*)(WT + (size_t)c * 256 + kc * 16 + hf * 8);
            acc[ct] = MFMA(a, bw, acc[ct]);
        }
    }
#pragma unroll
    for (int ct = 0; ct < 4; ++ct) {
        int c = cblk * 128 + ct * 32 + l31;
        float bvv = bias[c];
        int hh = c >> 8, d = c & 255;
#pragma unroll
        for (int r = 0; r < 16; ++r) {
            int m = m0 + (r & 3) + 8 * (r >> 2) + 4 * hf;
            int b = m >> 11, n = m & 2047;
            Ob[((size_t)(b * 2 + hh) * 2048 + n) * 256 + d] = bf16_rne(acc[ct][r] + bvv);
        }
    }
}

// ---------------------------------------------------------------------------
// k1_v: V^T[bh][d][n] = (x @ Wv + bv)^T via swapped MFMA: D[c][n] = WvT * x^T
// grid (128 n-tiles, 4 c-blocks).
// ---------------------------------------------------------------------------
__global__ __launch_bounds__(256) void k1_v(const float* __restrict__ x,
        const unsigned short* __restrict__ WvT, const float* __restrict__ bv,
        unsigned short* __restrict__ VTb) {
    const int w = threadIdx.x >> 6, l = threadIdx.x & 63;
    const int l31 = l & 31, hf = l >> 5;
    const int n0 = blockIdx.x * 128;
    const int c0 = blockIdx.y * 128 + w * 32;
    f32x16 acc[4];
#pragma unroll
    for (int i = 0; i < 4; ++i) acc[i] = zero16();
#pragma unroll
    for (int kc = 0; kc < 16; ++kc) {
        bf16x8 a = *(const bf16x8*)(WvT + (size_t)(c0 + l31) * 256 + kc * 16 + hf * 8);
#pragma unroll
        for (int nt = 0; nt < 4; ++nt) {
            bf16x8 bfr = ldx8(x + (size_t)(n0 + nt * 32 + l31) * 256 + kc * 16 + hf * 8);
            acc[nt] = MFMA(a, bfr, acc[nt]);
        }
    }
#pragma unroll
    for (int r = 0; r < 16; ++r) {
        int c = c0 + (r & 3) + 8 * (r >> 2) + 4 * hf;
        float bvv = bv[c];
        int hh = c >> 8, d = c & 255;
#pragma unroll
        for (int nt = 0; nt < 4; ++nt) {
            int m = n0 + nt * 32 + l31;
            int b = m >> 11, nl = m & 2047;
            VTb[((size_t)(b * 2 + hh) * 256 + d) * 2048 + nl] = bf16_rne(acc[nt][r] + bvv);
        }
    }
}

// ---------------------------------------------------------------------------
// k2_attn: flash attention. 4 waves x 32 q-rows (block = 128 q), KBLK=32.
// Swapped S = mfma(K, Q) -> D[key][q] (softmax lane-local). P transposed to
// the PV A-operand via cvt_pk_bf16 + v_permlane32_swap. K/V tiles double-
// buffered in LDS with 8B-granular XOR swizzle (conflict-free ds_read_b64).
// Defer-max online softmax (rescale only when max jumps > 8/ln2).
// ---------------------------------------------------------------------------
__global__ __launch_bounds__(256, 1) void k2_attn(
        const unsigned short* __restrict__ Qb, const unsigned short* __restrict__ Kb,
        const unsigned short* __restrict__ VTb, const float* __restrict__ bias2,
        unsigned short* __restrict__ AO) {
    __shared__ char kt[2][16384];  // [buf][32 key rows x 512B], 8B-swizzled
    __shared__ char vt[2][16384];  // [buf][256 d rows x 64B],   8B-swizzled
    const int tid = threadIdx.x;
    const int w = tid >> 6, l = tid & 63;
    const int l31 = l & 31, hf = l >> 5;
    const int bh = blockIdx.y, b = bh >> 1, h = bh & 1;
    const int q0 = blockIdx.x * 128 + w * 32;

    const unsigned short* Kbh = Kb + (size_t)bh * (2048 * 256);
    const unsigned short* Vbh = VTb + (size_t)bh * (256 * 2048);
    const float* b2 = bias2 + b * 2048;

    // Q fragments held in registers (64 VGPR)
    bf16x8 qf[16];
#pragma unroll
    for (int kc = 0; kc < 16; ++kc)
        qf[kc] = *(const bf16x8*)(Qb + (size_t)bh * (2048 * 256) +
                                  (size_t)(q0 + l31) * 256 + kc * 16 + hf * 8);

    f32x16 O[8];
#pragma unroll
    for (int dt = 0; dt < 8; ++dt) O[dt] = zero16();
    float m2 = -3.0e38f, lsum = 0.0f;

    const float c1 = 0.08838834764831845f * 1.4426950408889634f;  // scale*log2e
    const float THR2 = 11.541560327f;                             // 8*log2e

    const int krow = tid >> 3, kseg = tid & 7;  // K staging: 64B per thread
    const int vrow = tid;                       // V staging: 64B per thread
    const int swk = krow & 15;
    const int swv = (vrow >> 1) & 7;

    uint4 kr[4], vr[4];
    // ---- prologue: stage tile 0 into buf 0
    {
        const uint4* gk = (const uint4*)(Kbh + (size_t)krow * 256 + kseg * 32);
        const uint4* gv = (const uint4*)(Vbh + (size_t)vrow * 2048);
#pragma unroll
        for (int j = 0; j < 4; ++j) { kr[j] = gk[j]; vr[j] = gv[j]; }
        char* kb = kt[0]; char* vb = vt[0];
#pragma unroll
        for (int j = 0; j < 4; ++j) {
            int c8 = kseg * 8 + j * 2;
            *(uint2*)(kb + krow * 512 + (((c8) ^ swk) << 3)) = make_uint2(kr[j].x, kr[j].y);
            *(uint2*)(kb + krow * 512 + (((c8 + 1) ^ swk) << 3)) = make_uint2(kr[j].z, kr[j].w);
        }
#pragma unroll
        for (int j = 0; j < 4; ++j) {
            int c8 = j * 2;
            *(uint2*)(vb + vrow * 64 + (((c8) ^ swv) << 3)) = make_uint2(vr[j].x, vr[j].y);
            *(uint2*)(vb + vrow * 64 + (((c8 + 1) ^ swv) << 3)) = make_uint2(vr[j].z, vr[j].w);
        }
    }
    __syncthreads();

    for (int it = 0; it < 64; ++it) {
        const int cur = it & 1;
        if (it < 63) {  // issue next-tile global loads early (hide latency)
            int k0 = (it + 1) * 32;
            const uint4* gk = (const uint4*)(Kbh + (size_t)(k0 + krow) * 256 + kseg * 32);
            const uint4* gv = (const uint4*)(Vbh + (size_t)vrow * 2048 + k0);
#pragma unroll
            for (int j = 0; j < 4; ++j) { kr[j] = gk[j]; vr[j] = gv[j]; }
        }
        const char* kb = kt[cur];
        const char* vb = vt[cur];

        // ---- S = K.Q^T over d=256 (two independent acc chains)
        f32x16 s0 = zero16(), s1 = zero16();
#pragma unroll
        for (int kc = 0; kc < 16; kc += 2) {
            {
                int c8 = kc * 4 + hf * 2, sw = l31 & 15;
                uint2 a0 = *(const uint2*)(kb + l31 * 512 + (((c8) ^ sw) << 3));
                uint2 a1 = *(const uint2*)(kb + l31 * 512 + (((c8 + 1) ^ sw) << 3));
                s0 = MFMA(mk8(a0.x, a0.y, a1.x, a1.y), qf[kc], s0);
            }
            {
                int c8 = (kc + 1) * 4 + hf * 2, sw = l31 & 15;
                uint2 a0 = *(const uint2*)(kb + l31 * 512 + (((c8) ^ sw) << 3));
                uint2 a1 = *(const uint2*)(kb + l31 * 512 + (((c8 + 1) ^ sw) << 3));
                s1 = MFMA(mk8(a0.x, a0.y, a1.x, a1.y), qf[kc + 1], s1);
            }
        }

        // ---- online softmax (lane-local keys; per-lane q = l31)
        float p[16], tmax = -3.0e38f;
#pragma unroll
        for (int r = 0; r < 16; ++r) {
            int key = it * 32 + (r & 3) + 8 * (r >> 2) + 4 * hf;
            p[r] = (s0[r] + s1[r]) * c1 + b2[key];
            tmax = fmaxf(tmax, p[r]);
        }
        tmax = fmaxf(tmax, __shfl_xor(tmax, 32));
        if (__any(tmax > m2 + THR2)) {
            float mnew = fmaxf(m2, tmax);
            float f = __builtin_amdgcn_exp2f(m2 - mnew);
            m2 = mnew;
            lsum *= f;
#pragma unroll
            for (int r = 0; r < 16; ++r) {
                float fr = __shfl(f, (r & 3) + 8 * (r >> 2) + 4 * hf);
#pragma unroll
                for (int dt = 0; dt < 8; ++dt) O[dt][r] *= fr;
            }
        }
        float psum = 0.0f;
#pragma unroll
        for (int r = 0; r < 16; ++r) {
            p[r] = __builtin_amdgcn_exp2f(p[r] - m2);
            psum += p[r];
        }
        lsum += psum + __shfl_xor(psum, 32);

        // ---- P[key][q] -> A-operand P[q][k] via cvt_pk + permlane32_swap
        uint32_t a0 = cvt_pk_bf16(p[0], p[1]),   b0 = cvt_pk_bf16(p[4], p[5]);
        uint32_t a1 = cvt_pk_bf16(p[2], p[3]),   b1 = cvt_pk_bf16(p[6], p[7]);
        uint32_t a2 = cvt_pk_bf16(p[8], p[9]),   b2w = cvt_pk_bf16(p[12], p[13]);
        uint32_t a3 = cvt_pk_bf16(p[10], p[11]), b3 = cvt_pk_bf16(p[14], p[15]);
        asm volatile("v_permlane32_swap_b32 %0, %1" : "+v"(a0), "+v"(b0));
        asm volatile("v_permlane32_swap_b32 %0, %1" : "+v"(a1), "+v"(b1));
        asm volatile("v_permlane32_swap_b32 %0, %1" : "+v"(a2), "+v"(b2w));
        asm volatile("v_permlane32_swap_b32 %0, %1" : "+v"(a3), "+v"(b3));
        bf16x8 pa0 = mk8(a0, a1, b0, b1);   // keys 0..15
        bf16x8 pa1 = mk8(a2, a3, b2w, b3);  // keys 16..31

        // ---- O += P.V (8 independent acc chains)
#pragma unroll
        for (int dt = 0; dt < 8; ++dt) {
            int d = l31 + 32 * dt;
            int sv = (d >> 1) & 7;
            {
                int c8 = hf * 2;
                uint2 v0 = *(const uint2*)(vb + d * 64 + (((c8) ^ sv) << 3));
                uint2 v1 = *(const uint2*)(vb + d * 64 + (((c8 + 1) ^ sv) << 3));
                O[dt] = MFMA(pa0, mk8(v0.x, v0.y, v1.x, v1.y), O[dt]);
            }
            {
                int c8 = 4 + hf * 2;
                uint2 v0 = *(const uint2*)(vb + d * 64 + (((c8) ^ sv) << 3));
                uint2 v1 = *(const uint2*)(vb + d * 64 + (((c8 + 1) ^ sv) << 3));
                O[dt] = MFMA(pa1, mk8(v0.x, v0.y, v1.x, v1.y), O[dt]);
            }
        }

        __syncthreads();  // all waves done reading buf cur before overwriting cur^1 next
        if (it < 63) {
            char* kb2 = kt[cur ^ 1]; char* vb2 = vt[cur ^ 1];
#pragma unroll
            for (int j = 0; j < 4; ++j) {
                int c8 = kseg * 8 + j * 2;
                *(uint2*)(kb2 + krow * 512 + (((c8) ^ swk) << 3)) = make_uint2(kr[j].x, kr[j].y);
                *(uint2*)(kb2 + krow * 512 + (((c8 + 1) ^ swk) << 3)) = make_uint2(kr[j].z, kr[j].w);
            }
#pragma unroll
            for (int j = 0; j < 4; ++j) {
                int c8 = j * 2;
                *(uint2*)(vb2 + vrow * 64 + (((c8) ^ swv) << 3)) = make_uint2(vr[j].x, vr[j].y);
                *(uint2*)(vb2 + vrow * 64 + (((c8 + 1) ^ swv) << 3)) = make_uint2(vr[j].z, vr[j].w);
            }
        }
        __syncthreads();
    }

    // ---- epilogue: normalize by l and store AO[b][n][h*256+d] bf16
    float rl[16];
#pragma unroll
    for (int r = 0; r < 16; ++r) {
        float lr = __shfl(lsum, (r & 3) + 8 * (r >> 2) + 4 * hf);
        rl[r] = 1.0f / lr;
    }
    unsigned short* aop = AO + (size_t)b * 2048 * 512;
#pragma unroll
    for (int dt = 0; dt < 8; ++dt) {
        int d = l31 + 32 * dt;
#pragma unroll
        for (int r = 0; r < 16; ++r) {
            int q = q0 + (r & 3) + 8 * (r >> 2) + 4 * hf;
            aop[(size_t)q * 512 + h * 256 + d] = bf16_rne(O[dt][r] * rl[r]);
        }
    }
}

// ---------------------------------------------------------------------------
// k3_out: out[m][c] = AO[m][:] @ Wm[:][c] + bm[c]; mout[m][c] = mask[m].
// grid (128 m-tiles, 2 c-blocks).
// ---------------------------------------------------------------------------
__global__ __launch_bounds__(256) void k3_out(const unsigned short* __restrict__ AO,
        const unsigned short* __restrict__ WmT, const float* __restrict__ bm,
        const int* __restrict__ mask, float* __restrict__ outp, float* __restrict__ mout) {
    const int w = threadIdx.x >> 6, l = threadIdx.x & 63;
    const int l31 = l & 31, hf = l >> 5;
    const int m0 = blockIdx.x * 128 + w * 32;
    const int cblk = blockIdx.y;
    f32x16 acc[4];
#pragma unroll
    for (int i = 0; i < 4; ++i) acc[i] = zero16();
#pragma unroll
    for (int kc = 0; kc < 32; ++kc) {
        bf16x8 a = *(const bf16x8*)(AO + (size_t)(m0 + l31) * 512 + kc * 16 + hf * 8);
#pragma unroll
        for (int ct = 0; ct < 4; ++ct) {
            int c = cblk * 128 + ct * 32 + l31;
            bf16x8 bw = *(const bf16x8*)(WmT + (size_t)c * 512 + kc * 16 + hf * 8);
            acc[ct] = MFMA(a, bw, acc[ct]);
        }
    }
#pragma unroll
    for (int r = 0; r < 16; ++r) {
        int m = m0 + (r & 3) + 8 * (r >> 2) + 4 * hf;
        float mv = mask[m] ? 1.0f : 0.0f;
#pragma unroll
        for (int ct = 0; ct < 4; ++ct) {
            int c = cblk * 128 + ct * 32 + l31;
            outp[(size_t)m * 256 + c] = acc[ct][r] + bm[c];
            mout[(size_t)m * 256 + c] = mv;
        }
    }
}

// ---------------------------------------------------------------------------
extern "C" void kernel_launch(void* const* d_in, const int* in_sizes, int n_in,
                              void* d_out, int out_size, void* d_ws, size_t ws_size,
                              hipStream_t stream) {
    const float* x  = (const float*)d_in[0];
    const int* mask = (const int*)d_in[1];
    const float* Wq = (const float*)d_in[2];
    const float* bq = (const float*)d_in[3];
    const float* Wk = (const float*)d_in[4];
    const float* bk = (const float*)d_in[5];
    const float* Wv = (const float*)d_in[6];
    const float* bv = (const float*)d_in[7];
    const float* Wm = (const float*)d_in[8];
    const float* bm = (const float*)d_in[9];
    // d_in[10] = pool (always 1) -> identity pooling, ignored.

    char* ws = (char*)d_ws;
    unsigned short* Qb  = (unsigned short*)(ws);
    unsigned short* Kb  = (unsigned short*)(ws + 1 * 16777216);
    unsigned short* VTb = (unsigned short*)(ws + 2 * 16777216);
    unsigned short* AO  = (unsigned short*)(ws + 3 * 16777216);
    unsigned short* WqT = (unsigned short*)(ws + 4 * 16777216);
    unsigned short* WkT = (unsigned short*)(ws + 4 * 16777216 + 1 * 262144);
    unsigned short* WvT = (unsigned short*)(ws + 4 * 16777216 + 2 * 262144);
    unsigned short* WmT = (unsigned short*)(ws + 4 * 16777216 + 3 * 262144);
    float* bias2 = (float*)(ws + 4 * 16777216 + 4 * 262144);

    float* outp = (float*)d_out;
    float* mout = outp + 4194304;  // 8*2048*256

    k0_prep<<<dim3(2112), dim3(256), 0, stream>>>(Wq, Wk, Wv, Wm, mask,
                                                  WqT, WkT, WvT, WmT, bias2);
    k1_qk<<<dim3(128, 8), dim3(256), 0, stream>>>(x, WqT, WkT, bq, bk, Qb, Kb);
    k1_v<<<dim3(128, 4), dim3(256), 0, stream>>>(x, WvT, bv, VTb);
    k2_attn<<<dim3(16, 16), dim3(256), 0, stream>>>(Qb, Kb, VTb, bias2, AO);
    k3_out<<<dim3(128, 2), dim3(256), 0, stream>>>(AO, WmT, bm, mask, outp, mout);
}